// Round 6
// baseline (6613.399 us; speedup 1.0000x reference)
//
#include <hip/hip_runtime.h>
#include <hip/hip_fp16.h>

#define LOG2PI_F 1.8378770664093453f

typedef float f32x4 __attribute__((ext_vector_type(4)));
typedef unsigned int u32x4 __attribute__((ext_vector_type(4)));

// ---------------- f16 dot2 helper ----------------
typedef _Float16 hf2_t __attribute__((ext_vector_type(2)));

#if defined(__has_builtin)
#  if __has_builtin(__builtin_amdgcn_fdot2)
#    define USE_FDOT2 1
#  endif
#endif
#ifndef USE_FDOT2
#  define USE_FDOT2 0
#endif

__device__ __forceinline__ float fdot2(unsigned int a, unsigned int b, float c) {
#if USE_FDOT2
  return __builtin_amdgcn_fdot2(__builtin_bit_cast(hf2_t, a),
                                __builtin_bit_cast(hf2_t, b), c, false);
#else
  __half2 ha = __builtin_bit_cast(__half2, a);
  __half2 hb = __builtin_bit_cast(__half2, b);
  float2 fa = __half22float2(ha);
  float2 fb = __half22float2(hb);
  return c + fa.x * fb.x + fa.y * fb.y;
#endif
}

__device__ __forceinline__ unsigned int packh2(float lo, float hi) {
  unsigned int l = (unsigned int)__half_as_ushort(__float2half(lo));
  unsigned int h = (unsigned int)__half_as_ushort(__float2half(hi));
  return (h << 16) | l;
}

__device__ __forceinline__ float sigmoid_f(float x) { return 1.f / (1.f + __expf(-x)); }
__device__ __forceinline__ float silu_f(float x) { return x * sigmoid_f(x); }
__device__ __forceinline__ float softplus_f(float x) {
  return fmaxf(x, 0.f) + log1pf(__expf(-fabsf(x)));
}
__device__ __forceinline__ float tanh_f(float x) {
  float ax = fabsf(x);
  float e = __expf(2.f * ax);
  return copysignf(1.f - 2.f / (e + 1.f), x);
}

// ---------------- fused prep: 6 transposes + W_hh row-major f16 pack ----------------
__device__ __forceinline__ void tr_piece(const float* in, float* out, int R, int C,
                                         int i) {
  if (i < R * C) {
    int r = i / C, c = i % C;
    out[c * R + r] = in[i];
  }
}

__global__ void prep_kernel(const float* W_ih, const float* Wi1, const float* Wi2,
                            const float* Ws1, const float* Ws2, const float* Ws3,
                            const float* W_hh, float* WT_ih, float* WT1, float* WT2,
                            float* WTs1, float* WTs2, float* WTs3,
                            unsigned int* Wrow) {
  int blk = blockIdx.x;
  int tid = threadIdx.x;
  if (blk < 192) {
    tr_piece(W_ih, WT_ih, 768, 64, blk * 256 + tid);
  } else if (blk < 448) {
    tr_piece(Wi1, WT1, 256, 256, (blk - 192) * 256 + tid);
  } else if (blk < 512) {
    tr_piece(Wi2, WT2, 64, 256, (blk - 448) * 256 + tid);
  } else if (blk < 769) {
    tr_piece(Ws1, WTs1, 256, 257, (blk - 512) * 256 + tid);
  } else if (blk < 1025) {
    tr_piece(Ws2, WTs2, 256, 256, (blk - 769) * 256 + tid);
  } else if (blk < 1121) {
    tr_piece(Ws3, WTs3, 96, 256, (blk - 1025) * 256 + tid);
  } else {
    int i = (blk - 1121) * 256 + tid;  // i = r*128 + kp : row-major k-pairs
    if (i < 98304) {
      int r = i >> 7, kp = i & 127;
      Wrow[i] = packh2(W_hh[r * 256 + 2 * kp], W_hh[r * 256 + 2 * kp + 1]);
    }
  }
}

// ---------------- gi = x @ W_ih^T + b_ih (M-tile 8) ----------------
__global__ void gi_gemm(const float* __restrict__ x, const float* __restrict__ WT,
                        const float* __restrict__ bih, float* __restrict__ gi) {
  int m0 = blockIdx.x * 8;
  int g = threadIdx.x;
  __shared__ float xs[8][64];
  for (int i = g; i < 512; i += 256) xs[i >> 6][i & 63] = x[m0 * 64 + i];
  __syncthreads();
  float b0 = bih[g], b1 = bih[g + 256], b2 = bih[g + 512];
  float a0[8], a1[8], a2[8];
#pragma unroll
  for (int r = 0; r < 8; r++) { a0[r] = b0; a1[r] = b1; a2[r] = b2; }
  for (int k = 0; k < 64; k++) {
    const float* w = WT + k * 768;
    float w0 = w[g], w1 = w[g + 256], w2 = w[g + 512];
#pragma unroll
    for (int r = 0; r < 8; r++) {
      float xv = xs[r][k];
      a0[r] = fmaf(w0, xv, a0[r]);
      a1[r] = fmaf(w1, xv, a1[r]);
      a2[r] = fmaf(w2, xv, a2[r]);
    }
  }
#pragma unroll
  for (int r = 0; r < 8; r++) {
    float* o = gi + (m0 + r) * 768;
    o[g] = a0[r];
    o[g + 256] = a1[r];
    o[g + 512] = a2[r];
  }
}

// ---------------- GRU scan: v_dot2, weights register-resident ----------------
// 8 blocks x 512 threads. amdgpu_waves_per_eu(2,2): max occupancy clamped to
// 2 waves/EU so the allocator budgets 256 arch VGPRs (round-3 failure mode:
// min-only bound let it target 128 and spill the pinned weights).
// Thread layout: low (tid<256, d=tid): full r-row d + z-row d K-half1;
//                high (tid>=256):       full n-row d + z-row d K-half2.
// 192 weight dwords/thread, pinned via opaque asm (non-rematerializable).
__global__ __launch_bounds__(512)
__attribute__((amdgpu_waves_per_eu(2, 2))) void gru_kernel(
    const unsigned int* __restrict__ Wrow,  // [768][128] row-major packed f16 pairs
    const float* __restrict__ gi,           // [8,2048,768]
    const float* __restrict__ bhh,          // [768]
    float* __restrict__ h_seq)              // [8,2048,256]
{
  const int b = blockIdx.x;
  const int tid = threadIdx.x;
  const int d = tid & 255;
  const int half = tid >> 8;  // wave-uniform

  const int rf = half ? (512 + d) : d;
  const u32x4* af_ptr = (const u32x4*)(Wrow + rf * 128);
  const u32x4* az_ptr = (const u32x4*)(Wrow + (256 + d) * 128 + half * 64);

  u32x4 wf[32], wz[16];
#pragma unroll
  for (int i = 0; i < 32; i++) wf[i] = af_ptr[i];
#pragma unroll
  for (int i = 0; i < 16; i++) wz[i] = az_ptr[i];
  // pin: opaque asm per component — compiler cannot rematerialize the loads,
  // and with the (2,2) occupancy clamp it has 256 regs to keep them resident.
#pragma unroll
  for (int i = 0; i < 32; i++)
    asm("" : "+v"(wf[i].x), "+v"(wf[i].y), "+v"(wf[i].z), "+v"(wf[i].w));
#pragma unroll
  for (int i = 0; i < 16; i++)
    asm("" : "+v"(wz[i].x), "+v"(wz[i].y), "+v"(wz[i].z), "+v"(wz[i].w));

  __shared__ __align__(16) unsigned int hpk[2][128];
  __shared__ float als[512];
  if (tid < 128) hpk[0][tid] = 0u;

  float bf = 0.f, bz = 0.f, bn = 0.f;
  float h = 0.f;
  const float* gib = gi + b * 2048 * 768;
  float* hsb = h_seq + b * 2048 * 256;
  float gr = 0.f, gz = 0.f, gn = 0.f;
  if (half == 0) {
    bf = bhh[d];
    bz = bhh[256 + d];
    gr = gib[d];
    gz = gib[256 + d];
    gn = gib[512 + d];
  } else {
    bn = bhh[512 + d];
  }
  __syncthreads();

  for (int t = 0; t < 2048; t++) {
    float grn = 0.f, gzn = 0.f, gnn = 0.f;
    if (half == 0) {
      const float* g3 = gib + min(t + 1, 2047) * 768;
      grn = g3[d];
      gzn = g3[256 + d];
      gnn = g3[512 + d];
    }

    const u32x4* hp = (const u32x4*)hpk[t & 1];
    float a0 = 0.f, a1 = 0.f, z0 = 0.f, z1 = 0.f;
    if (half == 0) {
#pragma unroll
      for (int i = 0; i < 16; i += 2) {
        u32x4 h0 = hp[i], h1 = hp[i + 1];
        a0 = fdot2(wf[i].x, h0.x, a0);
        a0 = fdot2(wf[i].y, h0.y, a0);
        a0 = fdot2(wf[i].z, h0.z, a0);
        a0 = fdot2(wf[i].w, h0.w, a0);
        z0 = fdot2(wz[i].x, h0.x, z0);
        z0 = fdot2(wz[i].y, h0.y, z0);
        z0 = fdot2(wz[i].z, h0.z, z0);
        z0 = fdot2(wz[i].w, h0.w, z0);
        a1 = fdot2(wf[i + 1].x, h1.x, a1);
        a1 = fdot2(wf[i + 1].y, h1.y, a1);
        a1 = fdot2(wf[i + 1].z, h1.z, a1);
        a1 = fdot2(wf[i + 1].w, h1.w, a1);
        z1 = fdot2(wz[i + 1].x, h1.x, z1);
        z1 = fdot2(wz[i + 1].y, h1.y, z1);
        z1 = fdot2(wz[i + 1].z, h1.z, z1);
        z1 = fdot2(wz[i + 1].w, h1.w, z1);
      }
#pragma unroll
      for (int i = 16; i < 32; i += 2) {
        u32x4 h0 = hp[i], h1 = hp[i + 1];
        a0 = fdot2(wf[i].x, h0.x, a0);
        a0 = fdot2(wf[i].y, h0.y, a0);
        a0 = fdot2(wf[i].z, h0.z, a0);
        a0 = fdot2(wf[i].w, h0.w, a0);
        a1 = fdot2(wf[i + 1].x, h1.x, a1);
        a1 = fdot2(wf[i + 1].y, h1.y, a1);
        a1 = fdot2(wf[i + 1].z, h1.z, a1);
        a1 = fdot2(wf[i + 1].w, h1.w, a1);
      }
    } else {
#pragma unroll
      for (int i = 0; i < 16; i += 2) {
        u32x4 h0 = hp[i], h1 = hp[i + 1];
        a0 = fdot2(wf[i].x, h0.x, a0);
        a0 = fdot2(wf[i].y, h0.y, a0);
        a0 = fdot2(wf[i].z, h0.z, a0);
        a0 = fdot2(wf[i].w, h0.w, a0);
        a1 = fdot2(wf[i + 1].x, h1.x, a1);
        a1 = fdot2(wf[i + 1].y, h1.y, a1);
        a1 = fdot2(wf[i + 1].z, h1.z, a1);
        a1 = fdot2(wf[i + 1].w, h1.w, a1);
      }
#pragma unroll
      for (int i = 16; i < 32; i += 2) {
        u32x4 h0 = hp[i], h1 = hp[i + 1];
        a0 = fdot2(wf[i].x, h0.x, a0);
        a0 = fdot2(wf[i].y, h0.y, a0);
        a0 = fdot2(wf[i].z, h0.z, a0);
        a0 = fdot2(wf[i].w, h0.w, a0);
        z0 = fdot2(wz[i - 16].x, h0.x, z0);
        z0 = fdot2(wz[i - 16].y, h0.y, z0);
        z0 = fdot2(wz[i - 16].z, h0.z, z0);
        z0 = fdot2(wz[i - 16].w, h0.w, z0);
        a1 = fdot2(wf[i - 15].x, h1.x, a1);
        a1 = fdot2(wf[i - 15].y, h1.y, a1);
        a1 = fdot2(wf[i - 15].z, h1.z, a1);
        a1 = fdot2(wf[i - 15].w, h1.w, a1);
        z1 = fdot2(wz[i - 15].x, h1.x, z1);
        z1 = fdot2(wz[i - 15].y, h1.y, z1);
        z1 = fdot2(wz[i - 15].z, h1.z, z1);
        z1 = fdot2(wz[i - 15].w, h1.w, z1);
      }
    }
    float afull = a0 + a1;
    float zpart = z0 + z1;

    if (half) {
      als[d] = afull + bn;   // n-gate matvec + b_hh_n
      als[256 + d] = zpart;  // z half2
    }
    __syncthreads();

    if (half == 0) {
      float rv = sigmoid_f(gr + afull + bf);
      float zv = sigmoid_f(gz + zpart + als[256 + d] + bz);
      float nv = tanh_f(gn + rv * als[d]);
      float hn = (1.f - zv) * nv + zv * h;
      h = hn;
      hsb[t * 256 + d] = hn;
      float other = __shfl_xor(hn, 1);
      if ((d & 1) == 0) hpk[(t + 1) & 1][d >> 1] = packh2(hn, other);
    }
    gr = grn;
    gz = gzn;
    gn = gnn;
    __syncthreads();
  }
}

// ---------------- banded softmax attention + ctx = h_global + attn ----------------
#define AW 80
__global__ void attn_kernel(const float* __restrict__ h_seq, const float* __restrict__ t,
                            float* __restrict__ ctx) {
  const int blk = blockIdx.x;
  const int b = blk >> 7;
  const int k0 = (blk & 127) << 4;
  const int tid = threadIdx.x;

  __shared__ __align__(16) float ewT[176][16];
  __shared__ float ts[176];
  __shared__ float tks[16];
  __shared__ float rden[16];

  const float* tb = t + b * 2048;
  if (tid < 176) {
    int j = k0 - AW + tid;
    ts[tid] = tb[min(max(j, 0), 2047)];
  }
  if (tid < 16) tks[tid] = tb[k0 + tid];
  __syncthreads();

  for (int p = tid; p < 176 * 16; p += 256) {
    int kk = p & 15, jr = p >> 4;
    int j = k0 - AW + jr;
    float d = 2048.f * (tks[kk] - ts[jr]);
    float e = (j >= 0 && j < 2048) ? __expf(-d * d) : 0.f;
    ewT[jr][kk] = e;
  }
  __syncthreads();

  if (tid < 16) {
    float s = 0.f;
    for (int jr = 0; jr < 176; jr++) s += ewT[jr][tid];
    rden[tid] = 1.f / s;
  }
  __syncthreads();

  float acc[16];
#pragma unroll
  for (int kk = 0; kk < 16; kk++) acc[kk] = 0.f;

  const float* hb = h_seq + b * 2048 * 256;
  for (int jr = 0; jr < 176; jr++) {
    int j = min(max(k0 - AW + jr, 0), 2047);
    float hv = hb[j * 256 + tid];
    const float4* e4 = (const float4*)ewT[jr];
    float4 e0 = e4[0], e1 = e4[1], e2 = e4[2], e3 = e4[3];
    acc[0] = fmaf(e0.x, hv, acc[0]);   acc[1] = fmaf(e0.y, hv, acc[1]);
    acc[2] = fmaf(e0.z, hv, acc[2]);   acc[3] = fmaf(e0.w, hv, acc[3]);
    acc[4] = fmaf(e1.x, hv, acc[4]);   acc[5] = fmaf(e1.y, hv, acc[5]);
    acc[6] = fmaf(e1.z, hv, acc[6]);   acc[7] = fmaf(e1.w, hv, acc[7]);
    acc[8] = fmaf(e2.x, hv, acc[8]);   acc[9] = fmaf(e2.y, hv, acc[9]);
    acc[10] = fmaf(e2.z, hv, acc[10]); acc[11] = fmaf(e2.w, hv, acc[11]);
    acc[12] = fmaf(e3.x, hv, acc[12]); acc[13] = fmaf(e3.y, hv, acc[13]);
    acc[14] = fmaf(e3.z, hv, acc[14]); acc[15] = fmaf(e3.w, hv, acc[15]);
  }

  float hg = hb[2047 * 256 + tid];
  float* cb = ctx + (b * 2048 + k0) * 256 + tid;
#pragma unroll
  for (int kk = 0; kk < 16; kk++) cb[kk * 256] = hg + acc[kk] * rden[kk];
}

// ---------------- init head: m0, s0, log_q0 ----------------
__global__ void init_head(const float* __restrict__ ctx, const float* __restrict__ WT1,
                          const float* __restrict__ bi1, const float* __restrict__ WT2,
                          const float* __restrict__ bi2, const float* __restrict__ eps0,
                          float* __restrict__ m0s0, float* __restrict__ lq0) {
  int b = blockIdx.x;
  int g = threadIdx.x;
  __shared__ float xs[256], his[256], ms[64], red[32];
  xs[g] = ctx[(b * 2048) * 256 + g];
  __syncthreads();
  float acc = bi1[g];
#pragma unroll 8
  for (int k = 0; k < 256; k++) acc = fmaf(WT1[k * 256 + g], xs[k], acc);
  his[g] = silu_f(acc);
  __syncthreads();
  if (g < 64) {
    float a2 = bi2[g];
#pragma unroll 8
    for (int k = 0; k < 256; k++) a2 = fmaf(WT2[k * 64 + g], his[k], a2);
    float v = (g < 32) ? a2 : (softplus_f(a2) + 1e-6f);
    m0s0[b * 64 + g] = v;
    ms[g] = v;
  }
  __syncthreads();
  if (g < 32) {
    float m = ms[g], s = ms[32 + g];
    float c0 = m + s * eps0[b * 32 + g];
    float sc = fmaxf(s, 1e-12f);
    float z = (c0 - m) / sc;
    red[g] = z * z + 2.f * __logf(sc) + LOG2PI_F;
  }
  __syncthreads();
  if (g == 0) {
    float s = 0.f;
    for (int i = 0; i < 32; i++) s += red[i];
    lq0[b] = -0.5f * s;
  }
}

// ---------------- fused step head: 3 layers + A/Q epilogue ----------------
__global__ __launch_bounds__(256) void head_fused(
    const float* __restrict__ ctx, const float* __restrict__ WTs1,
    const float* __restrict__ bs1, const float* __restrict__ WTs2,
    const float* __restrict__ bs2, const float* __restrict__ WTs3,
    const float* __restrict__ bs3, const float* __restrict__ t,
    const float* __restrict__ eps, float* __restrict__ Aarr,
    float* __restrict__ Darr, float* __restrict__ Larr) {
  int m0 = blockIdx.x * 8;
  int g = threadIdx.x;
  __shared__ __align__(16) float As[8][256];
  __shared__ __align__(16) float Bs[8][256];
  __shared__ float Ps[8][96];
  __shared__ float trow[8];

#pragma unroll
  for (int r = 0; r < 8; r++) As[r][g] = ctx[(m0 + r) * 256 + g];
  if (g < 8) trow[g] = t[m0 + g];
  __syncthreads();

  {
    float b0 = bs1[g];
    float acc[8] = {b0, b0, b0, b0, b0, b0, b0, b0};
    for (int k4 = 0; k4 < 64; k4++) {
      const float* w = WTs1 + (k4 * 4) * 256 + g;
      float w0v = w[0], w1v = w[256], w2v = w[512], w3v = w[768];
#pragma unroll
      for (int r = 0; r < 8; r++) {
        float4 xv = *(const float4*)(&As[r][k4 * 4]);
        acc[r] = fmaf(w0v, xv.x, acc[r]);
        acc[r] = fmaf(w1v, xv.y, acc[r]);
        acc[r] = fmaf(w2v, xv.z, acc[r]);
        acc[r] = fmaf(w3v, xv.w, acc[r]);
      }
    }
    float we = WTs1[256 * 256 + g];
#pragma unroll
    for (int r = 0; r < 8; r++) Bs[r][g] = silu_f(fmaf(trow[r], we, acc[r]));
  }
  __syncthreads();

  {
    float b0 = bs2[g];
    float acc[8] = {b0, b0, b0, b0, b0, b0, b0, b0};
    for (int k4 = 0; k4 < 64; k4++) {
      const float* w = WTs2 + (k4 * 4) * 256 + g;
      float w0v = w[0], w1v = w[256], w2v = w[512], w3v = w[768];
#pragma unroll
      for (int r = 0; r < 8; r++) {
        float4 xv = *(const float4*)(&Bs[r][k4 * 4]);
        acc[r] = fmaf(w0v, xv.x, acc[r]);
        acc[r] = fmaf(w1v, xv.y, acc[r]);
        acc[r] = fmaf(w2v, xv.z, acc[r]);
        acc[r] = fmaf(w3v, xv.w, acc[r]);
      }
    }
#pragma unroll
    for (int r = 0; r < 8; r++) As[r][g] = silu_f(acc[r]);
  }
  __syncthreads();

  if (g < 96) {
    float b0 = bs3[g];
    float acc[8] = {b0, b0, b0, b0, b0, b0, b0, b0};
    for (int k4 = 0; k4 < 64; k4++) {
      const float* w = WTs3 + (k4 * 4) * 96 + g;
      float w0v = w[0], w1v = w[96], w2v = w[192], w3v = w[288];
#pragma unroll
      for (int r = 0; r < 8; r++) {
        float4 xv = *(const float4*)(&As[r][k4 * 4]);
        acc[r] = fmaf(w0v, xv.x, acc[r]);
        acc[r] = fmaf(w1v, xv.y, acc[r]);
        acc[r] = fmaf(w2v, xv.z, acc[r]);
        acc[r] = fmaf(w3v, xv.w, acc[r]);
      }
    }
#pragma unroll
    for (int r = 0; r < 8; r++) Ps[r][g] = acc[r];
  }
  __syncthreads();

  {
    int r = g >> 5, c = g & 31;
    int k = m0 + r;
    int b = k >> 11, kk = k & 2047;
    if (kk < 2047) {
      float mu = Ps[r][c];
      float kap = softplus_f(Ps[r][32 + c]) + 1e-6f;
      float sg = softplus_f(Ps[r][64 + c]) + 1e-6f;
      float dt = fmaxf(t[k + 1] - t[k], 1e-6f);
      float A = __expf(-kap * dt);
      float tkd = 2.f * kap * dt;
      float Qe = sg * sg * (1.f - A * A) / fmaxf(2.f * kap, 1e-12f);
      float kd = kap * dt;
      float Qt = sg * sg * dt * (1.f - kd + tkd * tkd * (1.f / 6.f));
      float var = fmaxf((tkd < 1e-6f) ? Qt : Qe, 1e-12f);
      float e = eps[(b * 2047 + kk) * 32 + c];
      int idx = (b * 2047 + kk) * 32 + c;
      Aarr[idx] = A;
      Darr[idx] = fmaf(mu, 1.f - A, e * sqrtf(var));
      Larr[idx] = e * e + __logf(var) + LOG2PI_F;
    }
  }
}

// ---------------- OU posterior: segmented scan over precomputed (A,d) ----------------
__global__ __launch_bounds__(1024) void ou_kernel(
    const float* __restrict__ Aarr, const float* __restrict__ Darr,
    const float* __restrict__ Larr, const float* __restrict__ eps0,
    const float* __restrict__ m0s0, const float* __restrict__ lq0,
    float* __restrict__ out) {
  const int b = blockIdx.x;
  const int c = threadIdx.x & 31;
  const int s = threadIdx.x >> 5;
  const int k0 = s * 64;
  const int k1 = min(k0 + 64, 2047);

  __shared__ float Ps[32][33], Ss[32][33], Cs[32][33], lqs[32][33];

  float P = 1.f, S = 0.f, lq = 0.f;
  for (int k = k0; k < k1; k++) {
    int idx = (b * 2047 + k) * 32 + c;
    float A = Aarr[idx];
    float d = Darr[idx];
    S = fmaf(A, S, d);
    P *= A;
    lq += Larr[idx];
  }
  Ps[c][s] = P;
  Ss[c][s] = S;
  lqs[c][s] = lq;
  __syncthreads();

  if (s == 0) {
    float m0v = m0s0[b * 64 + c];
    float s0v = m0s0[b * 64 + 32 + c];
    float cc = fmaf(s0v, eps0[b * 32 + c], m0v);
    out[(b * 2048) * 32 + c] = cc;
    float lqt = 0.f;
    for (int i = 0; i < 32; i++) {
      Cs[c][i] = cc;
      cc = fmaf(Ps[c][i], cc, Ss[c][i]);
      lqt += lqs[c][i];
    }
    for (int off = 16; off >= 1; off >>= 1) lqt += __shfl_down(lqt, off, 32);
    if (c == 0) out[8 * 2048 * 32 + b] = lq0[b] - 0.5f * lqt;
  }
  __syncthreads();

  float cc = Cs[c][s];
  for (int k = k0; k < k1; k++) {
    int idx = (b * 2047 + k) * 32 + c;
    cc = fmaf(Aarr[idx], cc, Darr[idx]);
    out[(b * 2048 + k + 1) * 32 + c] = cc;
  }
}

// ---------------- launcher ----------------
extern "C" void kernel_launch(void* const* d_in, const int* in_sizes, int n_in,
                              void* d_out, int out_size, void* d_ws, size_t ws_size,
                              hipStream_t stream) {
  (void)in_sizes; (void)n_in; (void)out_size; (void)ws_size;
  const float* x    = (const float*)d_in[0];
  const float* t    = (const float*)d_in[1];
  const float* eps0 = (const float*)d_in[2];
  const float* eps  = (const float*)d_in[3];
  const float* W_ih = (const float*)d_in[4];
  const float* W_hh = (const float*)d_in[5];
  const float* b_ih = (const float*)d_in[6];
  const float* b_hh = (const float*)d_in[7];
  const float* Wi1  = (const float*)d_in[8];
  const float* bi1  = (const float*)d_in[9];
  const float* Wi2  = (const float*)d_in[10];
  const float* bi2  = (const float*)d_in[11];
  const float* Ws1  = (const float*)d_in[12];
  const float* bs1  = (const float*)d_in[13];
  const float* Ws2  = (const float*)d_in[14];
  const float* bs2  = (const float*)d_in[15];
  const float* Ws3  = (const float*)d_in[16];
  const float* bs3  = (const float*)d_in[17];
  float* out = (float*)d_out;
  float* ws = (float*)d_ws;

  float*        WT_ih = ws + 0;                        // 49152
  unsigned int* Wrow  = (unsigned int*)(ws + 49152);   // 98304
  float*        WT1   = ws + 147456;                   // 65536
  float*        WT2   = ws + 212992;                   // 16384
  float*        WTs1  = ws + 229376;                   // 65792
  float*        WTs2  = ws + 295168;                   // 65536
  float*        WTs3  = ws + 360704;                   // 24576
  float*        m0s0  = ws + 385280;                   // 512
  float*        lq0   = ws + 385792;                   // 8
  float*        gi    = ws + 385800;                   // 12582912
  float*        h_seq = gi + 12582912;                 // 4194304
  float*        ctx   = h_seq + 4194304;               // 4194304
  float*        Aarr = gi;                             // reuse gi after GRU
  float*        Darr = gi + 524032;
  float*        Larr = gi + 1048064;

  prep_kernel<<<1505, 256, 0, stream>>>(W_ih, Wi1, Wi2, Ws1, Ws2, Ws3, W_hh,
                                        WT_ih, WT1, WT2, WTs1, WTs2, WTs3, Wrow);
  gi_gemm<<<2048, 256, 0, stream>>>(x, WT_ih, b_ih, gi);
  gru_kernel<<<8, 512, 0, stream>>>(Wrow, gi, b_hh, h_seq);
  attn_kernel<<<1024, 256, 0, stream>>>(h_seq, t, ctx);
  init_head<<<8, 256, 0, stream>>>(ctx, WT1, bi1, WT2, bi2, eps0, m0s0, lq0);
  head_fused<<<2048, 256, 0, stream>>>(ctx, WTs1, bs1, WTs2, bs2, WTs3, bs3, t, eps,
                                       Aarr, Darr, Larr);
  ou_kernel<<<8, 1024, 0, stream>>>(Aarr, Darr, Larr, eps0, m0s0, lq0, out);
}

// Round 7
// 3603.919 us; speedup vs baseline: 1.8351x; 1.8351x over previous
//
#include <hip/hip_runtime.h>
#include <hip/hip_fp16.h>

#define LOG2PI_F 1.8378770664093453f

typedef float f32x4 __attribute__((ext_vector_type(4)));
typedef unsigned int u32x4 __attribute__((ext_vector_type(4)));

// ---------------- f16 dot2 helper ----------------
typedef _Float16 hf2_t __attribute__((ext_vector_type(2)));

#if defined(__has_builtin)
#  if __has_builtin(__builtin_amdgcn_fdot2)
#    define USE_FDOT2 1
#  endif
#endif
#ifndef USE_FDOT2
#  define USE_FDOT2 0
#endif

__device__ __forceinline__ float fdot2(unsigned int a, unsigned int b, float c) {
#if USE_FDOT2
  return __builtin_amdgcn_fdot2(__builtin_bit_cast(hf2_t, a),
                                __builtin_bit_cast(hf2_t, b), c, false);
#else
  __half2 ha = __builtin_bit_cast(__half2, a);
  __half2 hb = __builtin_bit_cast(__half2, b);
  float2 fa = __half22float2(ha);
  float2 fb = __half22float2(hb);
  return c + fa.x * fb.x + fa.y * fb.y;
#endif
}

__device__ __forceinline__ unsigned int packh2(float lo, float hi) {
  unsigned int l = (unsigned int)__half_as_ushort(__float2half(lo));
  unsigned int h = (unsigned int)__half_as_ushort(__float2half(hi));
  return (h << 16) | l;
}

__device__ __forceinline__ float sigmoid_f(float x) { return 1.f / (1.f + __expf(-x)); }
__device__ __forceinline__ float silu_f(float x) { return x * sigmoid_f(x); }
__device__ __forceinline__ float softplus_f(float x) {
  return fmaxf(x, 0.f) + log1pf(__expf(-fabsf(x)));
}
__device__ __forceinline__ float tanh_f(float x) {
  float ax = fabsf(x);
  float e = __expf(2.f * ax);
  return copysignf(1.f - 2.f / (e + 1.f), x);
}

// ---------------- fused prep: 6 transposes + W_hh row-major f16 pack ----------------
__device__ __forceinline__ void tr_piece(const float* in, float* out, int R, int C,
                                         int i) {
  if (i < R * C) {
    int r = i / C, c = i % C;
    out[c * R + r] = in[i];
  }
}

__global__ void prep_kernel(const float* W_ih, const float* Wi1, const float* Wi2,
                            const float* Ws1, const float* Ws2, const float* Ws3,
                            const float* W_hh, float* WT_ih, float* WT1, float* WT2,
                            float* WTs1, float* WTs2, float* WTs3,
                            unsigned int* Wrow) {
  int blk = blockIdx.x;
  int tid = threadIdx.x;
  if (blk < 192) {
    tr_piece(W_ih, WT_ih, 768, 64, blk * 256 + tid);
  } else if (blk < 448) {
    tr_piece(Wi1, WT1, 256, 256, (blk - 192) * 256 + tid);
  } else if (blk < 512) {
    tr_piece(Wi2, WT2, 64, 256, (blk - 448) * 256 + tid);
  } else if (blk < 769) {
    tr_piece(Ws1, WTs1, 256, 257, (blk - 512) * 256 + tid);
  } else if (blk < 1025) {
    tr_piece(Ws2, WTs2, 256, 256, (blk - 769) * 256 + tid);
  } else if (blk < 1121) {
    tr_piece(Ws3, WTs3, 96, 256, (blk - 1025) * 256 + tid);
  } else {
    int i = (blk - 1121) * 256 + tid;  // i = r*128 + kp : row-major k-pairs
    if (i < 98304) {
      int r = i >> 7, kp = i & 127;
      Wrow[i] = packh2(W_hh[r * 256 + 2 * kp], W_hh[r * 256 + 2 * kp + 1]);
    }
  }
}

// ---------------- gi = x @ W_ih^T + b_ih (M-tile 8) ----------------
__global__ void gi_gemm(const float* __restrict__ x, const float* __restrict__ WT,
                        const float* __restrict__ bih, float* __restrict__ gi) {
  int m0 = blockIdx.x * 8;
  int g = threadIdx.x;
  __shared__ float xs[8][64];
  for (int i = g; i < 512; i += 256) xs[i >> 6][i & 63] = x[m0 * 64 + i];
  __syncthreads();
  float b0 = bih[g], b1 = bih[g + 256], b2 = bih[g + 512];
  float a0[8], a1[8], a2[8];
#pragma unroll
  for (int r = 0; r < 8; r++) { a0[r] = b0; a1[r] = b1; a2[r] = b2; }
  for (int k = 0; k < 64; k++) {
    const float* w = WT + k * 768;
    float w0 = w[g], w1 = w[g + 256], w2 = w[g + 512];
#pragma unroll
    for (int r = 0; r < 8; r++) {
      float xv = xs[r][k];
      a0[r] = fmaf(w0, xv, a0[r]);
      a1[r] = fmaf(w1, xv, a1[r]);
      a2[r] = fmaf(w2, xv, a2[r]);
    }
  }
#pragma unroll
  for (int r = 0; r < 8; r++) {
    float* o = gi + (m0 + r) * 768;
    o[g] = a0[r];
    o[g + 256] = a1[r];
    o[g + 512] = a2[r];
  }
}

// ---------------- GRU scan: all weights register-resident (arch + AGPR) -----------
// 8 blocks x 256 threads (4 waves = 1 wave/SIMD). launch_bounds(256,1) declares
// min 1 wave/EU -> up to 512 unified regs/wave. Thread d owns rows d (r, 128 dw
// in arch VGPRs), 256+d (z) and 512+d (n) (256 dw in AGPRs, the architectural
// max). Zero per-step weight memory traffic; AGPR->VGPR copies are VALU.
__global__ __launch_bounds__(256, 1) void gru_kernel(
    const unsigned int* __restrict__ Wrow,  // [768][128] row-major packed f16 pairs
    const float* __restrict__ gi,           // [8,2048,768]
    const float* __restrict__ bhh,          // [768]
    float* __restrict__ h_seq)              // [8,2048,256]
{
  const int b = blockIdx.x;
  const int d = threadIdx.x;  // 0..255

  // r-row -> arch VGPRs
  u32x4 wr[32];
  const u32x4* rp = (const u32x4*)(Wrow + d * 128);
#pragma unroll
  for (int i = 0; i < 32; i++) wr[i] = rp[i];
#pragma unroll
  for (int i = 0; i < 32; i++)
    asm("" : "+v"(wr[i].x), "+v"(wr[i].y), "+v"(wr[i].z), "+v"(wr[i].w));

  // z-row + n-row -> AGPRs (256 dwords = full acc file)
  u32x4 wz[32], wn[32];
  const u32x4* zp = (const u32x4*)(Wrow + (256 + d) * 128);
  const u32x4* np = (const u32x4*)(Wrow + (512 + d) * 128);
#pragma unroll
  for (int i = 0; i < 32; i++) wz[i] = zp[i];
#pragma unroll
  for (int i = 0; i < 32; i++) wn[i] = np[i];
#pragma unroll
  for (int i = 0; i < 32; i++) asm("" : "+a"(wz[i]));
#pragma unroll
  for (int i = 0; i < 32; i++) asm("" : "+a"(wn[i]));

  __shared__ __align__(16) unsigned int hpk[2][128];
  if (d < 128) hpk[0][d] = 0u;

  const float br = bhh[d], bz = bhh[256 + d], bn = bhh[512 + d];
  float h = 0.f;
  const float* gib = gi + b * 2048 * 768;
  float* hsb = h_seq + b * 2048 * 256;
  float gr = gib[d], gz = gib[256 + d], gn = gib[512 + d];
  __syncthreads();

  for (int t = 0; t < 2048; t++) {
    // re-pin each iteration: keeps a->v copies inside the loop (LICM would
    // otherwise hoist 256 copies and blow the arch budget)
#pragma unroll
    for (int i = 0; i < 32; i++) asm("" : "+a"(wz[i]));
#pragma unroll
    for (int i = 0; i < 32; i++) asm("" : "+a"(wn[i]));

    const float* g3 = gib + min(t + 1, 2047) * 768;
    float grn = g3[d];
    float gzn = g3[256 + d];
    float gnn = g3[512 + d];

    const u32x4* hp = (const u32x4*)hpk[t & 1];
    float ar = 0.f, az = 0.f, an = 0.f;
#pragma unroll
    for (int i = 0; i < 32; i++) {
      u32x4 hv = hp[i];
      u32x4 z = wz[i];  // accvgpr_read
      u32x4 n = wn[i];  // accvgpr_read
      ar = fdot2(wr[i].x, hv.x, ar);
      ar = fdot2(wr[i].y, hv.y, ar);
      ar = fdot2(wr[i].z, hv.z, ar);
      ar = fdot2(wr[i].w, hv.w, ar);
      az = fdot2(z.x, hv.x, az);
      az = fdot2(z.y, hv.y, az);
      az = fdot2(z.z, hv.z, az);
      az = fdot2(z.w, hv.w, az);
      an = fdot2(n.x, hv.x, an);
      an = fdot2(n.y, hv.y, an);
      an = fdot2(n.z, hv.z, an);
      an = fdot2(n.w, hv.w, an);
    }

    float rv = sigmoid_f(gr + ar + br);
    float zv = sigmoid_f(gz + az + bz);
    float nv = tanh_f(gn + rv * (an + bn));
    float hn = (1.f - zv) * nv + zv * h;
    h = hn;
    hsb[t * 256 + d] = hn;
    float other = __shfl_xor(hn, 1);
    if ((d & 1) == 0) hpk[(t + 1) & 1][d >> 1] = packh2(hn, other);
    gr = grn;
    gz = gzn;
    gn = gnn;
    __syncthreads();
  }
}

// ---------------- banded softmax attention + ctx = h_global + attn ----------------
#define AW 80
__global__ void attn_kernel(const float* __restrict__ h_seq, const float* __restrict__ t,
                            float* __restrict__ ctx) {
  const int blk = blockIdx.x;
  const int b = blk >> 7;
  const int k0 = (blk & 127) << 4;
  const int tid = threadIdx.x;

  __shared__ __align__(16) float ewT[176][16];
  __shared__ float ts[176];
  __shared__ float tks[16];
  __shared__ float rden[16];

  const float* tb = t + b * 2048;
  if (tid < 176) {
    int j = k0 - AW + tid;
    ts[tid] = tb[min(max(j, 0), 2047)];
  }
  if (tid < 16) tks[tid] = tb[k0 + tid];
  __syncthreads();

  for (int p = tid; p < 176 * 16; p += 256) {
    int kk = p & 15, jr = p >> 4;
    int j = k0 - AW + jr;
    float d = 2048.f * (tks[kk] - ts[jr]);
    float e = (j >= 0 && j < 2048) ? __expf(-d * d) : 0.f;
    ewT[jr][kk] = e;
  }
  __syncthreads();

  if (tid < 16) {
    float s = 0.f;
    for (int jr = 0; jr < 176; jr++) s += ewT[jr][tid];
    rden[tid] = 1.f / s;
  }
  __syncthreads();

  float acc[16];
#pragma unroll
  for (int kk = 0; kk < 16; kk++) acc[kk] = 0.f;

  const float* hb = h_seq + b * 2048 * 256;
  for (int jr = 0; jr < 176; jr++) {
    int j = min(max(k0 - AW + jr, 0), 2047);
    float hv = hb[j * 256 + tid];
    const float4* e4 = (const float4*)ewT[jr];
    float4 e0 = e4[0], e1 = e4[1], e2 = e4[2], e3 = e4[3];
    acc[0] = fmaf(e0.x, hv, acc[0]);   acc[1] = fmaf(e0.y, hv, acc[1]);
    acc[2] = fmaf(e0.z, hv, acc[2]);   acc[3] = fmaf(e0.w, hv, acc[3]);
    acc[4] = fmaf(e1.x, hv, acc[4]);   acc[5] = fmaf(e1.y, hv, acc[5]);
    acc[6] = fmaf(e1.z, hv, acc[6]);   acc[7] = fmaf(e1.w, hv, acc[7]);
    acc[8] = fmaf(e2.x, hv, acc[8]);   acc[9] = fmaf(e2.y, hv, acc[9]);
    acc[10] = fmaf(e2.z, hv, acc[10]); acc[11] = fmaf(e2.w, hv, acc[11]);
    acc[12] = fmaf(e3.x, hv, acc[12]); acc[13] = fmaf(e3.y, hv, acc[13]);
    acc[14] = fmaf(e3.z, hv, acc[14]); acc[15] = fmaf(e3.w, hv, acc[15]);
  }

  float hg = hb[2047 * 256 + tid];
  float* cb = ctx + (b * 2048 + k0) * 256 + tid;
#pragma unroll
  for (int kk = 0; kk < 16; kk++) cb[kk * 256] = hg + acc[kk] * rden[kk];
}

// ---------------- init head: m0, s0, log_q0 ----------------
__global__ void init_head(const float* __restrict__ ctx, const float* __restrict__ WT1,
                          const float* __restrict__ bi1, const float* __restrict__ WT2,
                          const float* __restrict__ bi2, const float* __restrict__ eps0,
                          float* __restrict__ m0s0, float* __restrict__ lq0) {
  int b = blockIdx.x;
  int g = threadIdx.x;
  __shared__ float xs[256], his[256], ms[64], red[32];
  xs[g] = ctx[(b * 2048) * 256 + g];
  __syncthreads();
  float acc = bi1[g];
#pragma unroll 8
  for (int k = 0; k < 256; k++) acc = fmaf(WT1[k * 256 + g], xs[k], acc);
  his[g] = silu_f(acc);
  __syncthreads();
  if (g < 64) {
    float a2 = bi2[g];
#pragma unroll 8
    for (int k = 0; k < 256; k++) a2 = fmaf(WT2[k * 64 + g], his[k], a2);
    float v = (g < 32) ? a2 : (softplus_f(a2) + 1e-6f);
    m0s0[b * 64 + g] = v;
    ms[g] = v;
  }
  __syncthreads();
  if (g < 32) {
    float m = ms[g], s = ms[32 + g];
    float c0 = m + s * eps0[b * 32 + g];
    float sc = fmaxf(s, 1e-12f);
    float z = (c0 - m) / sc;
    red[g] = z * z + 2.f * __logf(sc) + LOG2PI_F;
  }
  __syncthreads();
  if (g == 0) {
    float s = 0.f;
    for (int i = 0; i < 32; i++) s += red[i];
    lq0[b] = -0.5f * s;
  }
}

// ---------------- fused step head: 3 layers + A/Q epilogue ----------------
__global__ __launch_bounds__(256) void head_fused(
    const float* __restrict__ ctx, const float* __restrict__ WTs1,
    const float* __restrict__ bs1, const float* __restrict__ WTs2,
    const float* __restrict__ bs2, const float* __restrict__ WTs3,
    const float* __restrict__ bs3, const float* __restrict__ t,
    const float* __restrict__ eps, float* __restrict__ Aarr,
    float* __restrict__ Darr, float* __restrict__ Larr) {
  int m0 = blockIdx.x * 8;
  int g = threadIdx.x;
  __shared__ __align__(16) float As[8][256];
  __shared__ __align__(16) float Bs[8][256];
  __shared__ float Ps[8][96];
  __shared__ float trow[8];

#pragma unroll
  for (int r = 0; r < 8; r++) As[r][g] = ctx[(m0 + r) * 256 + g];
  if (g < 8) trow[g] = t[m0 + g];
  __syncthreads();

  {
    float b0 = bs1[g];
    float acc[8] = {b0, b0, b0, b0, b0, b0, b0, b0};
    for (int k4 = 0; k4 < 64; k4++) {
      const float* w = WTs1 + (k4 * 4) * 256 + g;
      float w0v = w[0], w1v = w[256], w2v = w[512], w3v = w[768];
#pragma unroll
      for (int r = 0; r < 8; r++) {
        float4 xv = *(const float4*)(&As[r][k4 * 4]);
        acc[r] = fmaf(w0v, xv.x, acc[r]);
        acc[r] = fmaf(w1v, xv.y, acc[r]);
        acc[r] = fmaf(w2v, xv.z, acc[r]);
        acc[r] = fmaf(w3v, xv.w, acc[r]);
      }
    }
    float we = WTs1[256 * 256 + g];
#pragma unroll
    for (int r = 0; r < 8; r++) Bs[r][g] = silu_f(fmaf(trow[r], we, acc[r]));
  }
  __syncthreads();

  {
    float b0 = bs2[g];
    float acc[8] = {b0, b0, b0, b0, b0, b0, b0, b0};
    for (int k4 = 0; k4 < 64; k4++) {
      const float* w = WTs2 + (k4 * 4) * 256 + g;
      float w0v = w[0], w1v = w[256], w2v = w[512], w3v = w[768];
#pragma unroll
      for (int r = 0; r < 8; r++) {
        float4 xv = *(const float4*)(&Bs[r][k4 * 4]);
        acc[r] = fmaf(w0v, xv.x, acc[r]);
        acc[r] = fmaf(w1v, xv.y, acc[r]);
        acc[r] = fmaf(w2v, xv.z, acc[r]);
        acc[r] = fmaf(w3v, xv.w, acc[r]);
      }
    }
#pragma unroll
    for (int r = 0; r < 8; r++) As[r][g] = silu_f(acc[r]);
  }
  __syncthreads();

  if (g < 96) {
    float b0 = bs3[g];
    float acc[8] = {b0, b0, b0, b0, b0, b0, b0, b0};
    for (int k4 = 0; k4 < 64; k4++) {
      const float* w = WTs3 + (k4 * 4) * 96 + g;
      float w0v = w[0], w1v = w[96], w2v = w[192], w3v = w[288];
#pragma unroll
      for (int r = 0; r < 8; r++) {
        float4 xv = *(const float4*)(&As[r][k4 * 4]);
        acc[r] = fmaf(w0v, xv.x, acc[r]);
        acc[r] = fmaf(w1v, xv.y, acc[r]);
        acc[r] = fmaf(w2v, xv.z, acc[r]);
        acc[r] = fmaf(w3v, xv.w, acc[r]);
      }
    }
#pragma unroll
    for (int r = 0; r < 8; r++) Ps[r][g] = acc[r];
  }
  __syncthreads();

  {
    int r = g >> 5, c = g & 31;
    int k = m0 + r;
    int b = k >> 11, kk = k & 2047;
    if (kk < 2047) {
      float mu = Ps[r][c];
      float kap = softplus_f(Ps[r][32 + c]) + 1e-6f;
      float sg = softplus_f(Ps[r][64 + c]) + 1e-6f;
      float dt = fmaxf(t[k + 1] - t[k], 1e-6f);
      float A = __expf(-kap * dt);
      float tkd = 2.f * kap * dt;
      float Qe = sg * sg * (1.f - A * A) / fmaxf(2.f * kap, 1e-12f);
      float kd = kap * dt;
      float Qt = sg * sg * dt * (1.f - kd + tkd * tkd * (1.f / 6.f));
      float var = fmaxf((tkd < 1e-6f) ? Qt : Qe, 1e-12f);
      float e = eps[(b * 2047 + kk) * 32 + c];
      int idx = (b * 2047 + kk) * 32 + c;
      Aarr[idx] = A;
      Darr[idx] = fmaf(mu, 1.f - A, e * sqrtf(var));
      Larr[idx] = e * e + __logf(var) + LOG2PI_F;
    }
  }
}

// ---------------- OU posterior: segmented scan over precomputed (A,d) ----------------
__global__ __launch_bounds__(1024) void ou_kernel(
    const float* __restrict__ Aarr, const float* __restrict__ Darr,
    const float* __restrict__ Larr, const float* __restrict__ eps0,
    const float* __restrict__ m0s0, const float* __restrict__ lq0,
    float* __restrict__ out) {
  const int b = blockIdx.x;
  const int c = threadIdx.x & 31;
  const int s = threadIdx.x >> 5;
  const int k0 = s * 64;
  const int k1 = min(k0 + 64, 2047);

  __shared__ float Ps[32][33], Ss[32][33], Cs[32][33], lqs[32][33];

  float P = 1.f, S = 0.f, lq = 0.f;
  for (int k = k0; k < k1; k++) {
    int idx = (b * 2047 + k) * 32 + c;
    float A = Aarr[idx];
    float d = Darr[idx];
    S = fmaf(A, S, d);
    P *= A;
    lq += Larr[idx];
  }
  Ps[c][s] = P;
  Ss[c][s] = S;
  lqs[c][s] = lq;
  __syncthreads();

  if (s == 0) {
    float m0v = m0s0[b * 64 + c];
    float s0v = m0s0[b * 64 + 32 + c];
    float cc = fmaf(s0v, eps0[b * 32 + c], m0v);
    out[(b * 2048) * 32 + c] = cc;
    float lqt = 0.f;
    for (int i = 0; i < 32; i++) {
      Cs[c][i] = cc;
      cc = fmaf(Ps[c][i], cc, Ss[c][i]);
      lqt += lqs[c][i];
    }
    for (int off = 16; off >= 1; off >>= 1) lqt += __shfl_down(lqt, off, 32);
    if (c == 0) out[8 * 2048 * 32 + b] = lq0[b] - 0.5f * lqt;
  }
  __syncthreads();

  float cc = Cs[c][s];
  for (int k = k0; k < k1; k++) {
    int idx = (b * 2047 + k) * 32 + c;
    cc = fmaf(Aarr[idx], cc, Darr[idx]);
    out[(b * 2048 + k + 1) * 32 + c] = cc;
  }
}

// ---------------- launcher ----------------
extern "C" void kernel_launch(void* const* d_in, const int* in_sizes, int n_in,
                              void* d_out, int out_size, void* d_ws, size_t ws_size,
                              hipStream_t stream) {
  (void)in_sizes; (void)n_in; (void)out_size; (void)ws_size;
  const float* x    = (const float*)d_in[0];
  const float* t    = (const float*)d_in[1];
  const float* eps0 = (const float*)d_in[2];
  const float* eps  = (const float*)d_in[3];
  const float* W_ih = (const float*)d_in[4];
  const float* W_hh = (const float*)d_in[5];
  const float* b_ih = (const float*)d_in[6];
  const float* b_hh = (const float*)d_in[7];
  const float* Wi1  = (const float*)d_in[8];
  const float* bi1  = (const float*)d_in[9];
  const float* Wi2  = (const float*)d_in[10];
  const float* bi2  = (const float*)d_in[11];
  const float* Ws1  = (const float*)d_in[12];
  const float* bs1  = (const float*)d_in[13];
  const float* Ws2  = (const float*)d_in[14];
  const float* bs2  = (const float*)d_in[15];
  const float* Ws3  = (const float*)d_in[16];
  const float* bs3  = (const float*)d_in[17];
  float* out = (float*)d_out;
  float* ws = (float*)d_ws;

  float*        WT_ih = ws + 0;                        // 49152
  unsigned int* Wrow  = (unsigned int*)(ws + 49152);   // 98304
  float*        WT1   = ws + 147456;                   // 65536
  float*        WT2   = ws + 212992;                   // 16384
  float*        WTs1  = ws + 229376;                   // 65792
  float*        WTs2  = ws + 295168;                   // 65536
  float*        WTs3  = ws + 360704;                   // 24576
  float*        m0s0  = ws + 385280;                   // 512
  float*        lq0   = ws + 385792;                   // 8
  float*        gi    = ws + 385800;                   // 12582912
  float*        h_seq = gi + 12582912;                 // 4194304
  float*        ctx   = h_seq + 4194304;               // 4194304
  float*        Aarr = gi;                             // reuse gi after GRU
  float*        Darr = gi + 524032;
  float*        Larr = gi + 1048064;

  prep_kernel<<<1505, 256, 0, stream>>>(W_ih, Wi1, Wi2, Ws1, Ws2, Ws3, W_hh,
                                        WT_ih, WT1, WT2, WTs1, WTs2, WTs3, Wrow);
  gi_gemm<<<2048, 256, 0, stream>>>(x, WT_ih, b_ih, gi);
  gru_kernel<<<8, 256, 0, stream>>>(Wrow, gi, b_hh, h_seq);
  attn_kernel<<<1024, 256, 0, stream>>>(h_seq, t, ctx);
  init_head<<<8, 256, 0, stream>>>(ctx, WT1, bi1, WT2, bi2, eps0, m0s0, lq0);
  head_fused<<<2048, 256, 0, stream>>>(ctx, WTs1, bs1, WTs2, bs2, WTs3, bs3, t, eps,
                                       Aarr, Darr, Larr);
  ou_kernel<<<8, 1024, 0, stream>>>(Aarr, Darr, Larr, eps0, m0s0, lq0, out);
}